// Round 1
// baseline (782.347 us; speedup 1.0000x reference)
//
#include <hip/hip_runtime.h>
#include <hip/hip_bf16.h>

// MultimodalFusion: B=16384, S=3, D=512, H=8, HD=64, FF=2048
// Round 0: correctness-first MFMA pipeline.
//   K0 cast weights fp32->bf16
//   K1 x = feat+pos -> bf16 [rows,512]
//   K2 GEMM qkv = x @ w_in^T + b_in -> bf16 [rows,1536]
//   K3 attention per (b,head) wave -> bf16 o [rows,512]
//   K4 GEMM y = o @ w_out^T + b_out -> fp32 [rows,512]
//   K5 x1 = LN1(feat+pos + y) -> bf16 [rows,512]
//   K6 GEMM h = relu(x1 @ w1^T + b1) -> bf16 [rows,2048]
//   K7 GEMM f = h @ w2^T + b2 -> fp32 [rows,512]
//   K8 out[b] = mean_s LN2(x1 + f)
// ws aliasing: A region xbf->x1bf ; B region qkv->y->f ; C ob ; D h.
// Batch chunked (Bc multiple of 128) to fit ws_size; deterministic per call.

#define BTOT 16384
#define DD 512
#define EPS_ 1e-5f

typedef __attribute__((ext_vector_type(8))) short bf8v;
typedef __attribute__((ext_vector_type(4))) float f4v;

__device__ __forceinline__ unsigned short f2bf(float f) {
  unsigned int u = __builtin_bit_cast(unsigned int, f);
  u += 0x7fffu + ((u >> 16) & 1u);
  return (unsigned short)(u >> 16);
}
__device__ __forceinline__ float bf2f(unsigned short s) {
  unsigned int u = ((unsigned int)s) << 16;
  return __builtin_bit_cast(float, u);
}
__device__ __forceinline__ unsigned int pk2(float a, float b) {
  return (unsigned int)f2bf(a) | ((unsigned int)f2bf(b) << 16);
}

// ---------------- K0: weight cast ----------------
__global__ __launch_bounds__(256) void cast_w(const float* __restrict__ w,
                                              unsigned short* __restrict__ o, int n) {
  int i = (blockIdx.x * 256 + threadIdx.x) * 4;
  if (i >= n) return;
  float4 v = *(const float4*)&w[i];
  uint2 u; u.x = pk2(v.x, v.y); u.y = pk2(v.z, v.w);
  *(uint2*)&o[i] = u;
}

// ---------------- K1: build x = feat + pos -> bf16 ----------------
__global__ __launch_bounds__(256) void build_x(const float* __restrict__ f0,
                                               const float* __restrict__ f1,
                                               const float* __restrict__ f2,
                                               const float* __restrict__ pos,
                                               unsigned short* __restrict__ xbf, int b0) {
  int gi = blockIdx.x * 256 + threadIdx.x;
  int e = gi * 4;
  int r = e >> 9;
  int d = e & 511;
  int bl = r / 3, s = r - bl * 3;
  const float* f = (s == 0 ? f0 : (s == 1 ? f1 : f2)) + (size_t)(b0 + bl) * DD + d;
  const float* pp = pos + s * DD + d;
  float4 fv = *(const float4*)f;
  float4 pv = *(const float4*)pp;
  uint2 o; o.x = pk2(fv.x + pv.x, fv.y + pv.y); o.y = pk2(fv.z + pv.z, fv.w + pv.w);
  *(uint2*)&xbf[(size_t)r * DD + d] = o;
}

// ---------------- GEMM: C[M,N] = A[M,K] @ Bw[N,K]^T + bias ----------------
// 128x128 tile, 4 waves in 2x2, each wave 4x4 of 16x16x32 MFMA. BK=64.
// A-frag: lane holds A[m=lane&15][k=(lane>>4)*8 + j]; B-frag same with n=lane&15.
// C/D: col=lane&15, row=(lane>>4)*4+reg.  (guide-verified m89/m91/m92)
#define TM 128
#define TN 128
#define BKK 64
#define LDK 72  // +8 pad (16B) keeps uint4 align; 2-way LDS aliasing only (free)

template <int ACT, int OBF>
__global__ __launch_bounds__(256, 2) void gemm_bt(const unsigned short* __restrict__ A,
                                                  const unsigned short* __restrict__ Bw,
                                                  const float* __restrict__ bias,
                                                  void* __restrict__ C, int M, int N, int K) {
  __shared__ unsigned short lA[TM * LDK];
  __shared__ unsigned short lB[TN * LDK];
  const int tid = threadIdx.x;
  const int row0 = blockIdx.y * TM;
  const int col0 = blockIdx.x * TN;
  const int lane = tid & 63;
  const int wid = tid >> 6;
  const int wm = (wid >> 1) * 64;
  const int wn = (wid & 1) * 64;
  const int lr = lane & 15;
  const int lk = (lane >> 4) * 8;

  f4v acc[4][4];
#pragma unroll
  for (int i = 0; i < 4; i++)
#pragma unroll
    for (int j = 0; j < 4; j++) acc[i][j] = (f4v)0.f;

  const int r_st = tid >> 3;        // staging row (does r_st, r_st+32, +64, +96)
  const int k_st = (tid & 7) * 8;   // staging k offset (x8 bf16 = 16B)

  for (int k0 = 0; k0 < K; k0 += BKK) {
    const unsigned short* Ag = A + (size_t)(row0 + r_st) * K + k0 + k_st;
    const unsigned short* Bg = Bw + (size_t)(col0 + r_st) * K + k0 + k_st;
    unsigned short* la = &lA[r_st * LDK + k_st];
    unsigned short* lb = &lB[r_st * LDK + k_st];
#pragma unroll
    for (int i = 0; i < 4; i++) {
      *(uint4*)(la + i * 32 * LDK) = *(const uint4*)(Ag + (size_t)i * 32 * K);
      *(uint4*)(lb + i * 32 * LDK) = *(const uint4*)(Bg + (size_t)i * 32 * K);
    }
    __syncthreads();
#pragma unroll
    for (int kk = 0; kk < BKK; kk += 32) {
      bf8v af[4], bfr[4];
#pragma unroll
      for (int i = 0; i < 4; i++)
        af[i] = *(const bf8v*)&lA[(wm + i * 16 + lr) * LDK + kk + lk];
#pragma unroll
      for (int j = 0; j < 4; j++)
        bfr[j] = *(const bf8v*)&lB[(wn + j * 16 + lr) * LDK + kk + lk];
#pragma unroll
      for (int i = 0; i < 4; i++)
#pragma unroll
        for (int j = 0; j < 4; j++)
          acc[i][j] = __builtin_amdgcn_mfma_f32_16x16x32_bf16(af[i], bfr[j], acc[i][j], 0, 0, 0);
    }
    __syncthreads();
  }

#pragma unroll
  for (int j = 0; j < 4; j++) {
    int gcol = col0 + wn + j * 16 + lr;
    float bv = bias[gcol];
#pragma unroll
    for (int i = 0; i < 4; i++) {
#pragma unroll
      for (int r = 0; r < 4; r++) {
        int grow = row0 + wm + i * 16 + (lane >> 4) * 4 + r;
        float v = acc[i][j][r] + bv;
        if (ACT) v = fmaxf(v, 0.f);
        if (OBF)
          ((unsigned short*)C)[(size_t)grow * N + gcol] = f2bf(v);
        else
          ((float*)C)[(size_t)grow * N + gcol] = v;
      }
    }
  }
}

// ---------------- K3: attention, one wave per (b, head) ----------------
__global__ __launch_bounds__(512) void attn_k(const unsigned short* __restrict__ qkv,
                                              unsigned short* __restrict__ ob) {
  int b = blockIdx.x;
  int h = threadIdx.x >> 6;
  int lane = threadIdx.x & 63;
  size_t base = ((size_t)b * 3) * 1536 + h * 64 + lane;
  float q[3], k[3], v[3];
#pragma unroll
  for (int s = 0; s < 3; s++) {
    q[s] = bf2f(qkv[base + (size_t)s * 1536]);
    k[s] = bf2f(qkv[base + (size_t)s * 1536 + 512]);
    v[s] = bf2f(qkv[base + (size_t)s * 1536 + 1024]);
  }
  float sc[3][3];
#pragma unroll
  for (int qi = 0; qi < 3; qi++)
#pragma unroll
    for (int ki = 0; ki < 3; ki++) {
      float p = q[qi] * k[ki];
#pragma unroll
      for (int off = 32; off > 0; off >>= 1) p += __shfl_xor(p, off, 64);
      sc[qi][ki] = p * 0.125f;  // 1/sqrt(64)
    }
#pragma unroll
  for (int qi = 0; qi < 3; qi++) {
    float m = fmaxf(sc[qi][0], fmaxf(sc[qi][1], sc[qi][2]));
    float e0 = __expf(sc[qi][0] - m), e1 = __expf(sc[qi][1] - m), e2 = __expf(sc[qi][2] - m);
    float inv = 1.f / (e0 + e1 + e2);
    float o = (e0 * v[0] + e1 * v[1] + e2 * v[2]) * inv;
    ob[((size_t)b * 3 + qi) * DD + h * 64 + lane] = f2bf(o);
  }
}

// ---------------- K5: x1 = LN1(feat+pos + y) -> bf16; one wave per row -----
__global__ __launch_bounds__(256) void ln1_k(const float* __restrict__ y,
                                             const float* __restrict__ f0,
                                             const float* __restrict__ f1,
                                             const float* __restrict__ f2,
                                             const float* __restrict__ pos,
                                             const float* __restrict__ g,
                                             const float* __restrict__ be,
                                             unsigned short* __restrict__ x1, int b0) {
  int wid = threadIdx.x >> 6, lane = threadIdx.x & 63;
  int r = blockIdx.x * 4 + wid;
  int bl = r / 3, s = r - bl * 3;
  const float* f = (s == 0 ? f0 : (s == 1 ? f1 : f2)) + (size_t)(b0 + bl) * DD;
  const float* pp = pos + s * DD;
  const float* yy = y + (size_t)r * DD;
  int d = lane * 8;
  float x[8];
#pragma unroll
  for (int i = 0; i < 8; i++) x[i] = f[d + i] + pp[d + i] + yy[d + i];
  float su = 0.f, sq = 0.f;
#pragma unroll
  for (int i = 0; i < 8; i++) { su += x[i]; sq += x[i] * x[i]; }
#pragma unroll
  for (int off = 32; off > 0; off >>= 1) {
    su += __shfl_xor(su, off, 64);
    sq += __shfl_xor(sq, off, 64);
  }
  float mean = su * (1.f / 512.f);
  float var = sq * (1.f / 512.f) - mean * mean;
  float rs = rsqrtf(var + EPS_);
  unsigned short o[8];
#pragma unroll
  for (int i = 0; i < 8; i++) o[i] = f2bf((x[i] - mean) * rs * g[d + i] + be[d + i]);
  uint4 pack;
  pack.x = (unsigned)o[0] | ((unsigned)o[1] << 16);
  pack.y = (unsigned)o[2] | ((unsigned)o[3] << 16);
  pack.z = (unsigned)o[4] | ((unsigned)o[5] << 16);
  pack.w = (unsigned)o[6] | ((unsigned)o[7] << 16);
  *(uint4*)&x1[(size_t)r * DD + d] = pack;
}

// ---------------- K8: out[b] = mean_s LN2(x1 + f) ----------------
__global__ __launch_bounds__(192) void final_k(const unsigned short* __restrict__ x1,
                                               const float* __restrict__ ff,
                                               const float* __restrict__ g,
                                               const float* __restrict__ be,
                                               float* __restrict__ out) {
  __shared__ float t3[3][DD];
  int w = threadIdx.x >> 6, lane = threadIdx.x & 63;
  int b = blockIdx.x;
  size_t r = (size_t)b * 3 + w;
  int d = lane * 8;
  float x[8];
#pragma unroll
  for (int i = 0; i < 8; i++) x[i] = bf2f(x1[r * DD + d + i]) + ff[r * DD + d + i];
  float su = 0.f, sq = 0.f;
#pragma unroll
  for (int i = 0; i < 8; i++) { su += x[i]; sq += x[i] * x[i]; }
#pragma unroll
  for (int off = 32; off > 0; off >>= 1) {
    su += __shfl_xor(su, off, 64);
    sq += __shfl_xor(sq, off, 64);
  }
  float mean = su * (1.f / 512.f);
  float var = sq * (1.f / 512.f) - mean * mean;
  float rs = rsqrtf(var + EPS_);
#pragma unroll
  for (int i = 0; i < 8; i++) t3[w][d + i] = (x[i] - mean) * rs * g[d + i] + be[d + i];
  __syncthreads();
  for (int dd = threadIdx.x; dd < DD; dd += 192)
    out[(size_t)b * DD + dd] = (t3[0][dd] + t3[1][dd] + t3[2][dd]) * (1.f / 3.f);
}

extern "C" void kernel_launch(void* const* d_in, const int* in_sizes, int n_in,
                              void* d_out, int out_size, void* d_ws, size_t ws_size,
                              hipStream_t stream) {
  const float* feat0 = (const float*)d_in[0];
  const float* feat1 = (const float*)d_in[1];
  const float* feat2 = (const float*)d_in[2];
  const float* pos   = (const float*)d_in[3];
  const float* w_in  = (const float*)d_in[4];
  const float* b_in  = (const float*)d_in[5];
  const float* w_out = (const float*)d_in[6];
  const float* b_out = (const float*)d_in[7];
  const float* ln1_g = (const float*)d_in[8];
  const float* ln1_b = (const float*)d_in[9];
  const float* w1    = (const float*)d_in[10];
  const float* b1    = (const float*)d_in[11];
  const float* w2    = (const float*)d_in[12];
  const float* b2    = (const float*)d_in[13];
  const float* ln2_g = (const float*)d_in[14];
  const float* ln2_b = (const float*)d_in[15];
  float* out = (float*)d_out;

  // ---- workspace carve ----
  char* p = (char*)d_ws;
  unsigned short* w_in_b  = (unsigned short*)p; p += (size_t)1536 * 512 * 2;
  unsigned short* w_out_b = (unsigned short*)p; p += (size_t)512 * 512 * 2;
  unsigned short* w1_b    = (unsigned short*)p; p += (size_t)2048 * 512 * 2;
  unsigned short* w2_b    = (unsigned short*)p; p += (size_t)512 * 2048 * 2;
  size_t wbytes = (size_t)(p - (char*)d_ws);

  // chunk count: smallest that fits ws (deterministic across calls)
  int nch = 16;
  for (int c = 1; c <= 16; c <<= 1) {
    size_t rows = (size_t)(BTOT / c) * 3;
    if (wbytes + rows * 9216 <= ws_size) { nch = c; break; }
  }
  const int Bc = BTOT / nch;
  const int rows = Bc * 3;

  unsigned short* xbf = (unsigned short*)p;            // also x1bf (aliased in time)
  char* regB = p + (size_t)rows * 1024;                // qkv (bf16) -> y (f32) -> f (f32)
  unsigned short* ob = (unsigned short*)(regB + (size_t)rows * 3072);
  unsigned short* hb = ob + (size_t)rows * 512;        // h bf16 [rows,2048]

  // K0: weight casts
  cast_w<<<768, 256, 0, stream>>>(w_in, w_in_b, 1536 * 512);
  cast_w<<<256, 256, 0, stream>>>(w_out, w_out_b, 512 * 512);
  cast_w<<<1024, 256, 0, stream>>>(w1, w1_b, 2048 * 512);
  cast_w<<<1024, 256, 0, stream>>>(w2, w2_b, 512 * 2048);

  for (int c = 0; c < nch; c++) {
    int b0 = c * Bc;
    build_x<<<rows / 2, 256, 0, stream>>>(feat0, feat1, feat2, pos, xbf, b0);
    gemm_bt<0, 1><<<dim3(12, rows / 128), 256, 0, stream>>>(
        xbf, w_in_b, b_in, (void*)regB, rows, 1536, 512);
    attn_k<<<Bc, 512, 0, stream>>>((const unsigned short*)regB, ob);
    gemm_bt<0, 0><<<dim3(4, rows / 128), 256, 0, stream>>>(
        ob, w_out_b, b_out, (void*)regB, rows, 512, 512);  // y f32 (aliases qkv)
    ln1_k<<<rows / 4, 256, 0, stream>>>((const float*)regB, feat0, feat1, feat2, pos,
                                        ln1_g, ln1_b, xbf, b0);
    gemm_bt<1, 1><<<dim3(16, rows / 128), 256, 0, stream>>>(
        xbf, w1_b, b1, (void*)hb, rows, 2048, 512);
    gemm_bt<0, 0><<<dim3(4, rows / 128), 256, 0, stream>>>(
        hb, w2_b, b2, (void*)regB, rows, 512, 2048);  // f f32
    final_k<<<Bc, 192, 0, stream>>>(xbf, (const float*)regB, ln2_g, ln2_b,
                                    out + (size_t)b0 * DD);
  }
}

// Round 2
// 769.834 us; speedup vs baseline: 1.0163x; 1.0163x over previous
//
#include <hip/hip_runtime.h>
#include <hip/hip_bf16.h>

// MultimodalFusion: B=16384, S=3, D=512, H=8, HD=64, FF=2048
// Round 2: GEMM staging via __builtin_amdgcn_global_load_lds (width=16) into
// unpadded LDS with XOR k-chunk swizzle (conflict-free ds_read_b128).
// Pipeline otherwise identical to round 1:
//   K0 cast weights fp32->bf16
//   K1 x = feat+pos -> bf16 [rows,512]
//   K2 GEMM qkv = x @ w_in^T + b_in -> bf16 [rows,1536]
//   K3 attention per (b,head) wave -> bf16 o [rows,512]
//   K4 GEMM y = o @ w_out^T + b_out -> fp32 [rows,512]
//   K5 x1 = LN1(feat+pos + y) -> bf16 [rows,512]
//   K6 GEMM h = relu(x1 @ w1^T + b1) -> bf16 [rows,2048]
//   K7 GEMM f = h @ w2^T + b2 -> fp32 [rows,512]
//   K8 out[b] = mean_s LN2(x1 + f)

#define BTOT 16384
#define DD 512
#define EPS_ 1e-5f

typedef __attribute__((ext_vector_type(8))) short bf8v;
typedef __attribute__((ext_vector_type(4))) float f4v;

__device__ __forceinline__ unsigned short f2bf(float f) {
  unsigned int u = __builtin_bit_cast(unsigned int, f);
  u += 0x7fffu + ((u >> 16) & 1u);
  return (unsigned short)(u >> 16);
}
__device__ __forceinline__ float bf2f(unsigned short s) {
  unsigned int u = ((unsigned int)s) << 16;
  return __builtin_bit_cast(float, u);
}
__device__ __forceinline__ unsigned int pk2(float a, float b) {
  return (unsigned int)f2bf(a) | ((unsigned int)f2bf(b) << 16);
}

// async global->LDS, 16B per lane; lds dst is wave-uniform base + lane*16
#define GLDS16(gp, lp)                                                   \
  __builtin_amdgcn_global_load_lds(                                      \
      (const __attribute__((address_space(1))) void*)(gp),               \
      (__attribute__((address_space(3))) void*)(lp), 16, 0, 0)

// ---------------- K0: weight cast ----------------
__global__ __launch_bounds__(256) void cast_w(const float* __restrict__ w,
                                              unsigned short* __restrict__ o, int n) {
  int i = (blockIdx.x * 256 + threadIdx.x) * 4;
  if (i >= n) return;
  float4 v = *(const float4*)&w[i];
  uint2 u; u.x = pk2(v.x, v.y); u.y = pk2(v.z, v.w);
  *(uint2*)&o[i] = u;
}

// ---------------- K1: build x = feat + pos -> bf16 ----------------
__global__ __launch_bounds__(256) void build_x(const float* __restrict__ f0,
                                               const float* __restrict__ f1,
                                               const float* __restrict__ f2,
                                               const float* __restrict__ pos,
                                               unsigned short* __restrict__ xbf, int b0) {
  int gi = blockIdx.x * 256 + threadIdx.x;
  int e = gi * 4;
  int r = e >> 9;
  int d = e & 511;
  int bl = r / 3, s = r - bl * 3;
  const float* f = (s == 0 ? f0 : (s == 1 ? f1 : f2)) + (size_t)(b0 + bl) * DD + d;
  const float* pp = pos + s * DD + d;
  float4 fv = *(const float4*)f;
  float4 pv = *(const float4*)pp;
  uint2 o; o.x = pk2(fv.x + pv.x, fv.y + pv.y); o.y = pk2(fv.z + pv.z, fv.w + pv.w);
  *(uint2*)&xbf[(size_t)r * DD + d] = o;
}

// ---------------- GEMM: C[M,N] = A[M,K] @ Bw[N,K]^T + bias ----------------
// 128x128 tile, 4 waves 2x2, each wave 4x4 of 16x16x32 MFMA, BK=64.
// LDS tile: unpadded [128][64] bf16, but the k-chunk (8 bf16 = 16B) at
// row r, chunk q lives at slot (q ^ (r&7)) — XOR swizzle applied on the
// GLOBAL address side during global_load_lds staging, so fragment
// ds_read_b128 spreads across all 32 banks (2-way max = free).
// Staging: wave w, iter i stages chunk c=w*4+i (rows c*8..c*8+7, 1 KiB);
// lane l -> row c*8+(l>>3), global k-chunk (l&7)^(l>>3), LDS auto +l*16B.
#define TM 128
#define TN 128
#define BKK 64

template <int ACT, int OBF>
__global__ __launch_bounds__(256, 2) void gemm_bt(const unsigned short* __restrict__ A,
                                                  const unsigned short* __restrict__ Bw,
                                                  const float* __restrict__ bias,
                                                  void* __restrict__ C, int M, int N, int K) {
  __shared__ unsigned short lA[TM * BKK];
  __shared__ unsigned short lB[TN * BKK];
  const int tid = threadIdx.x;
  const int row0 = blockIdx.y * TM;
  const int col0 = blockIdx.x * TN;
  const int lane = tid & 63;
  const int wid = tid >> 6;
  const int wm = (wid >> 1) * 64;
  const int wn = (wid & 1) * 64;
  const int lr = lane & 15;
  const int ql = lane >> 4;       // k-chunk index within 32-k step (0..3)
  const int xk = lr & 7;          // fragment-read XOR key (row&7)

  f4v acc[4][4];
#pragma unroll
  for (int i = 0; i < 4; i++)
#pragma unroll
    for (int j = 0; j < 4; j++) acc[i][j] = (f4v)0.f;

  // staging geometry
  const int c0 = wid * 4;                    // first chunk of this wave
  const int srow = lane >> 3;                // 0..7 within chunk
  const int sq = (lane & 7) ^ srow;          // swizzled global k-chunk
  const unsigned short* Ag0 = A + (size_t)(row0 + c0 * 8 + srow) * K + sq * 8;
  const unsigned short* Bg0 = Bw + (size_t)(col0 + c0 * 8 + srow) * K + sq * 8;
  unsigned short* lA0 = &lA[c0 * 512];       // wave-uniform; +i*512 per iter
  unsigned short* lB0 = &lB[c0 * 512];

  for (int k0 = 0; k0 < K; k0 += BKK) {
#pragma unroll
    for (int i = 0; i < 4; i++) {
      GLDS16(Ag0 + (size_t)(i * 8) * K + k0, lA0 + i * 512);
      GLDS16(Bg0 + (size_t)(i * 8) * K + k0, lB0 + i * 512);
    }
    __syncthreads();
#pragma unroll
    for (int kk = 0; kk < BKK; kk += 32) {
      const int slot = (((kk >> 3) + ql) ^ xk) * 8;
      bf8v af[4], bfr[4];
#pragma unroll
      for (int i = 0; i < 4; i++)
        af[i] = *(const bf8v*)&lA[(wm + i * 16 + lr) * BKK + slot];
#pragma unroll
      for (int j = 0; j < 4; j++)
        bfr[j] = *(const bf8v*)&lB[(wn + j * 16 + lr) * BKK + slot];
#pragma unroll
      for (int i = 0; i < 4; i++)
#pragma unroll
        for (int j = 0; j < 4; j++)
          acc[i][j] = __builtin_amdgcn_mfma_f32_16x16x32_bf16(af[i], bfr[j], acc[i][j], 0, 0, 0);
    }
    __syncthreads();
  }

#pragma unroll
  for (int j = 0; j < 4; j++) {
    int gcol = col0 + wn + j * 16 + lr;
    float bv = bias[gcol];
#pragma unroll
    for (int i = 0; i < 4; i++) {
#pragma unroll
      for (int r = 0; r < 4; r++) {
        int grow = row0 + wm + i * 16 + (lane >> 4) * 4 + r;
        float v = acc[i][j][r] + bv;
        if (ACT) v = fmaxf(v, 0.f);
        if (OBF)
          ((unsigned short*)C)[(size_t)grow * N + gcol] = f2bf(v);
        else
          ((float*)C)[(size_t)grow * N + gcol] = v;
      }
    }
  }
}

// ---------------- K3: attention, one wave per (b, head) ----------------
__global__ __launch_bounds__(512) void attn_k(const unsigned short* __restrict__ qkv,
                                              unsigned short* __restrict__ ob) {
  int b = blockIdx.x;
  int h = threadIdx.x >> 6;
  int lane = threadIdx.x & 63;
  size_t base = ((size_t)b * 3) * 1536 + h * 64 + lane;
  float q[3], k[3], v[3];
#pragma unroll
  for (int s = 0; s < 3; s++) {
    q[s] = bf2f(qkv[base + (size_t)s * 1536]);
    k[s] = bf2f(qkv[base + (size_t)s * 1536 + 512]);
    v[s] = bf2f(qkv[base + (size_t)s * 1536 + 1024]);
  }
  float sc[3][3];
#pragma unroll
  for (int qi = 0; qi < 3; qi++)
#pragma unroll
    for (int ki = 0; ki < 3; ki++) {
      float p = q[qi] * k[ki];
#pragma unroll
      for (int off = 32; off > 0; off >>= 1) p += __shfl_xor(p, off, 64);
      sc[qi][ki] = p * 0.125f;  // 1/sqrt(64)
    }
#pragma unroll
  for (int qi = 0; qi < 3; qi++) {
    float m = fmaxf(sc[qi][0], fmaxf(sc[qi][1], sc[qi][2]));
    float e0 = __expf(sc[qi][0] - m), e1 = __expf(sc[qi][1] - m), e2 = __expf(sc[qi][2] - m);
    float inv = 1.f / (e0 + e1 + e2);
    float o = (e0 * v[0] + e1 * v[1] + e2 * v[2]) * inv;
    ob[((size_t)b * 3 + qi) * DD + h * 64 + lane] = f2bf(o);
  }
}

// ---------------- K5: x1 = LN1(feat+pos + y) -> bf16; one wave per row -----
__global__ __launch_bounds__(256) void ln1_k(const float* __restrict__ y,
                                             const float* __restrict__ f0,
                                             const float* __restrict__ f1,
                                             const float* __restrict__ f2,
                                             const float* __restrict__ pos,
                                             const float* __restrict__ g,
                                             const float* __restrict__ be,
                                             unsigned short* __restrict__ x1, int b0) {
  int wid = threadIdx.x >> 6, lane = threadIdx.x & 63;
  int r = blockIdx.x * 4 + wid;
  int bl = r / 3, s = r - bl * 3;
  const float* f = (s == 0 ? f0 : (s == 1 ? f1 : f2)) + (size_t)(b0 + bl) * DD;
  const float* pp = pos + s * DD;
  const float* yy = y + (size_t)r * DD;
  int d = lane * 8;
  float x[8];
#pragma unroll
  for (int i = 0; i < 8; i++) x[i] = f[d + i] + pp[d + i] + yy[d + i];
  float su = 0.f, sq = 0.f;
#pragma unroll
  for (int i = 0; i < 8; i++) { su += x[i]; sq += x[i] * x[i]; }
#pragma unroll
  for (int off = 32; off > 0; off >>= 1) {
    su += __shfl_xor(su, off, 64);
    sq += __shfl_xor(sq, off, 64);
  }
  float mean = su * (1.f / 512.f);
  float var = sq * (1.f / 512.f) - mean * mean;
  float rs = rsqrtf(var + EPS_);
  unsigned short o[8];
#pragma unroll
  for (int i = 0; i < 8; i++) o[i] = f2bf((x[i] - mean) * rs * g[d + i] + be[d + i]);
  uint4 pack;
  pack.x = (unsigned)o[0] | ((unsigned)o[1] << 16);
  pack.y = (unsigned)o[2] | ((unsigned)o[3] << 16);
  pack.z = (unsigned)o[4] | ((unsigned)o[5] << 16);
  pack.w = (unsigned)o[6] | ((unsigned)o[7] << 16);
  *(uint4*)&x1[(size_t)r * DD + d] = pack;
}

// ---------------- K8: out[b] = mean_s LN2(x1 + f) ----------------
__global__ __launch_bounds__(192) void final_k(const unsigned short* __restrict__ x1,
                                               const float* __restrict__ ff,
                                               const float* __restrict__ g,
                                               const float* __restrict__ be,
                                               float* __restrict__ out) {
  __shared__ float t3[3][DD];
  int w = threadIdx.x >> 6, lane = threadIdx.x & 63;
  int b = blockIdx.x;
  size_t r = (size_t)b * 3 + w;
  int d = lane * 8;
  float x[8];
#pragma unroll
  for (int i = 0; i < 8; i++) x[i] = bf2f(x1[r * DD + d + i]) + ff[r * DD + d + i];
  float su = 0.f, sq = 0.f;
#pragma unroll
  for (int i = 0; i < 8; i++) { su += x[i]; sq += x[i] * x[i]; }
#pragma unroll
  for (int off = 32; off > 0; off >>= 1) {
    su += __shfl_xor(su, off, 64);
    sq += __shfl_xor(sq, off, 64);
  }
  float mean = su * (1.f / 512.f);
  float var = sq * (1.f / 512.f) - mean * mean;
  float rs = rsqrtf(var + EPS_);
#pragma unroll
  for (int i = 0; i < 8; i++) t3[w][d + i] = (x[i] - mean) * rs * g[d + i] + be[d + i];
  __syncthreads();
  for (int dd = threadIdx.x; dd < DD; dd += 192)
    out[(size_t)b * DD + dd] = (t3[0][dd] + t3[1][dd] + t3[2][dd]) * (1.f / 3.f);
}

extern "C" void kernel_launch(void* const* d_in, const int* in_sizes, int n_in,
                              void* d_out, int out_size, void* d_ws, size_t ws_size,
                              hipStream_t stream) {
  const float* feat0 = (const float*)d_in[0];
  const float* feat1 = (const float*)d_in[1];
  const float* feat2 = (const float*)d_in[2];
  const float* pos   = (const float*)d_in[3];
  const float* w_in  = (const float*)d_in[4];
  const float* b_in  = (const float*)d_in[5];
  const float* w_out = (const float*)d_in[6];
  const float* b_out = (const float*)d_in[7];
  const float* ln1_g = (const float*)d_in[8];
  const float* ln1_b = (const float*)d_in[9];
  const float* w1    = (const float*)d_in[10];
  const float* b1    = (const float*)d_in[11];
  const float* w2    = (const float*)d_in[12];
  const float* b2    = (const float*)d_in[13];
  const float* ln2_g = (const float*)d_in[14];
  const float* ln2_b = (const float*)d_in[15];
  float* out = (float*)d_out;

  // ---- workspace carve ----
  char* p = (char*)d_ws;
  unsigned short* w_in_b  = (unsigned short*)p; p += (size_t)1536 * 512 * 2;
  unsigned short* w_out_b = (unsigned short*)p; p += (size_t)512 * 512 * 2;
  unsigned short* w1_b    = (unsigned short*)p; p += (size_t)2048 * 512 * 2;
  unsigned short* w2_b    = (unsigned short*)p; p += (size_t)512 * 2048 * 2;
  size_t wbytes = (size_t)(p - (char*)d_ws);

  // chunk count: smallest that fits ws (deterministic across calls)
  int nch = 16;
  for (int c = 1; c <= 16; c <<= 1) {
    size_t rows = (size_t)(BTOT / c) * 3;
    if (wbytes + rows * 9216 <= ws_size) { nch = c; break; }
  }
  const int Bc = BTOT / nch;
  const int rows = Bc * 3;

  unsigned short* xbf = (unsigned short*)p;            // also x1bf (aliased in time)
  char* regB = p + (size_t)rows * 1024;                // qkv (bf16) -> y (f32) -> f (f32)
  unsigned short* ob = (unsigned short*)(regB + (size_t)rows * 3072);
  unsigned short* hb = ob + (size_t)rows * 512;        // h bf16 [rows,2048]

  // K0: weight casts
  cast_w<<<768, 256, 0, stream>>>(w_in, w_in_b, 1536 * 512);
  cast_w<<<256, 256, 0, stream>>>(w_out, w_out_b, 512 * 512);
  cast_w<<<1024, 256, 0, stream>>>(w1, w1_b, 2048 * 512);
  cast_w<<<1024, 256, 0, stream>>>(w2, w2_b, 512 * 2048);

  for (int c = 0; c < nch; c++) {
    int b0 = c * Bc;
    build_x<<<rows / 2, 256, 0, stream>>>(feat0, feat1, feat2, pos, xbf, b0);
    gemm_bt<0, 1><<<dim3(12, rows / 128), 256, 0, stream>>>(
        xbf, w_in_b, b_in, (void*)regB, rows, 1536, 512);
    attn_k<<<Bc, 512, 0, stream>>>((const unsigned short*)regB, ob);
    gemm_bt<0, 0><<<dim3(4, rows / 128), 256, 0, stream>>>(
        ob, w_out_b, b_out, (void*)regB, rows, 512, 512);  // y f32 (aliases qkv)
    ln1_k<<<rows / 4, 256, 0, stream>>>((const float*)regB, feat0, feat1, feat2, pos,
                                        ln1_g, ln1_b, xbf, b0);
    gemm_bt<1, 1><<<dim3(16, rows / 128), 256, 0, stream>>>(
        xbf, w1_b, b1, (void*)hb, rows, 2048, 512);
    gemm_bt<0, 0><<<dim3(4, rows / 128), 256, 0, stream>>>(
        hb, w2_b, b2, (void*)regB, rows, 512, 2048);  // f f32
    final_k<<<Bc, 192, 0, stream>>>(xbf, (const float*)regB, ln2_g, ln2_b,
                                    out + (size_t)b0 * DD);
  }
}